// Round 1
// baseline (3867.083 us; speedup 1.0000x reference)
//
#include <hip/hip_runtime.h>
#include <cstdint>
#include <cstddef>

#define IN_DIM 512
#define HID 512
#define OUT_DIM 256
#define BN_EPS 1e-5f

__device__ __forceinline__ float gelu_f(float x) {
    return 0.5f * x * (1.0f + erff(x * 0.70710678118654752f));
}

// ---------------- utility: zero ----------------
__global__ void zero_kernel(int* __restrict__ p, int n) {
    int i = blockIdx.x * 256 + threadIdx.x;
    if (i < n) p[i] = 0;
}

// ---------------- CSR build ----------------
__global__ void count_edges(const int* __restrict__ row, int ne, int* __restrict__ counts) {
    int e = blockIdx.x * 256 + threadIdx.x;
    if (e < ne) atomicAdd(&counts[row[e]], 1);
}

template<int BS>
__global__ void scan_block(const int* __restrict__ in, int n,
                           int* __restrict__ out, int* __restrict__ bsums) {
    __shared__ int tmp[BS];
    int t = threadIdx.x;
    int gid = blockIdx.x * BS + t;
    int v = (gid < n) ? in[gid] : 0;
    tmp[t] = v;
    __syncthreads();
    for (int off = 1; off < BS; off <<= 1) {
        int add = (t >= off) ? tmp[t - off] : 0;
        __syncthreads();
        tmp[t] += add;
        __syncthreads();
    }
    if (gid < n) out[gid] = tmp[t] - v;   // exclusive
    if (t == BS - 1 && bsums) bsums[blockIdx.x] = tmp[t];
}

__global__ void scan_add(int* __restrict__ row_start, int* __restrict__ cur_off,
                         const int* __restrict__ bsums, int n) {
    int gid = blockIdx.x * 256 + threadIdx.x;
    if (gid < n) {
        int v = row_start[gid] + bsums[blockIdx.x];
        row_start[gid] = v;
        cur_off[gid] = v;
    }
}

__global__ void scatter_edges(const int* __restrict__ row, const int* __restrict__ col,
                              const float* __restrict__ val, int ne,
                              int* __restrict__ cur_off, int* __restrict__ scol,
                              float* __restrict__ sval) {
    int e = blockIdx.x * 256 + threadIdx.x;
    if (e < ne) {
        int r = row[e];
        int p = atomicAdd(&cur_off[r], 1);
        scol[p] = col[e];
        sval[p] = val[e];
    }
}

// ---------------- fp32 tiled GEMM, C[M,N] = A[M,K] @ B[K,N] (+epilogue) ----------------
// EPI: 0 = none, 1 = relu(acc + bias), 2 = extra * sigmoid(acc + bias)
template<int EPI>
__global__ __launch_bounds__(256) void gemm_kernel(
    const float* __restrict__ A, const float* __restrict__ B,
    float* __restrict__ C, const float* __restrict__ bias,
    const float* __restrict__ extra, int M, int N, int K)
{
    constexpr int TM = 64, TN = 64, TK = 16;
    __shared__ float As[TK][TM];
    __shared__ float Bs[TK][TN];

    int tid = threadIdx.x;
    int tx = tid & 15, ty = tid >> 4;
    int row0 = blockIdx.x * TM, col0 = blockIdx.y * TN;

    int arow = tid >> 2;          // 0..63
    int akcol = (tid & 3) * 4;    // 0,4,8,12
    int brow = tid >> 4;          // 0..15
    int bcol = (tid & 15) * 4;

    float acc[4][4] = {};

    for (int k0 = 0; k0 < K; k0 += TK) {
        float4 av;
        if (row0 + arow < M)
            av = *(const float4*)&A[(size_t)(row0 + arow) * K + k0 + akcol];
        else
            av = make_float4(0.f, 0.f, 0.f, 0.f);
        As[akcol + 0][arow] = av.x;
        As[akcol + 1][arow] = av.y;
        As[akcol + 2][arow] = av.z;
        As[akcol + 3][arow] = av.w;
        float4 bv = *(const float4*)&B[(size_t)(k0 + brow) * N + col0 + bcol];
        *(float4*)&Bs[brow][bcol] = bv;
        __syncthreads();
#pragma unroll
        for (int kk = 0; kk < TK; ++kk) {
            float4 a4 = *(const float4*)&As[kk][ty * 4];
            float4 b4 = *(const float4*)&Bs[kk][tx * 4];
            float a[4] = {a4.x, a4.y, a4.z, a4.w};
            float b[4] = {b4.x, b4.y, b4.z, b4.w};
#pragma unroll
            for (int i = 0; i < 4; ++i)
#pragma unroll
                for (int j = 0; j < 4; ++j)
                    acc[i][j] = fmaf(a[i], b[j], acc[i][j]);
        }
        __syncthreads();
    }

#pragma unroll
    for (int i = 0; i < 4; ++i) {
        int r = row0 + ty * 4 + i;
        if (r >= M) continue;
        int c0 = col0 + tx * 4;
        float4 outv;
        float o[4];
#pragma unroll
        for (int j = 0; j < 4; ++j) o[j] = acc[i][j];
        if (EPI == 1) {
#pragma unroll
            for (int j = 0; j < 4; ++j) o[j] = fmaxf(o[j] + bias[c0 + j], 0.f);
        } else if (EPI == 2) {
            float4 ex = *(const float4*)&extra[(size_t)r * N + c0];
            float e[4] = {ex.x, ex.y, ex.z, ex.w};
#pragma unroll
            for (int j = 0; j < 4; ++j) {
                float s = o[j] + bias[c0 + j];
                o[j] = e[j] * (1.f / (1.f + expf(-s)));
            }
        }
        outv.x = o[0]; outv.y = o[1]; outv.z = o[2]; outv.w = o[3];
        *(float4*)&C[(size_t)r * N + c0] = outv;
    }
}

// ---------------- SpMM (CSR, gather) + bias + GELU ----------------
template<int F>
__global__ __launch_bounds__(256) void spmm_bias_gelu(
    const float* __restrict__ sup, const int* __restrict__ scol,
    const float* __restrict__ sval, const int* __restrict__ row_start,
    const int* __restrict__ counts, const float* __restrict__ bias,
    float* __restrict__ out, int n)
{
    constexpr int NV = F / 256;
    int row = blockIdx.x;
    int tid = threadIdx.x;
    int start = row_start[row];
    int nnz = counts[row];
    float acc[NV] = {};
    for (int j = 0; j < nnz; ++j) {
        int c = scol[start + j];
        float v = sval[start + j];
#pragma unroll
        for (int k = 0; k < NV; ++k)
            acc[k] = fmaf(v, sup[(size_t)c * F + tid + k * 256], acc[k]);
    }
#pragma unroll
    for (int k = 0; k < NV; ++k) {
        int f = tid + k * 256;
        out[(size_t)row * F + f] = gelu_f(acc[k] + bias[f]);
    }
}

// ---------------- BatchNorm ----------------
template<int F>
__global__ __launch_bounds__(256) void bn_reduce(const float* __restrict__ x, int n,
                                                 float* __restrict__ ssum, float* __restrict__ ssq)
{
    constexpr int NV = F / 256;
    int tid = threadIdx.x;
    int r0 = blockIdx.x * 256;
    int rend = min(r0 + 256, n);
    float s[NV] = {}, q[NV] = {};
    for (int r = r0; r < rend; ++r) {
#pragma unroll
        for (int k = 0; k < NV; ++k) {
            float v = x[(size_t)r * F + tid + k * 256];
            s[k] += v;
            q[k] += v * v;
        }
    }
#pragma unroll
    for (int k = 0; k < NV; ++k) {
        atomicAdd(&ssum[tid + k * 256], s[k]);
        atomicAdd(&ssq[tid + k * 256], q[k]);
    }
}

template<int F>
__global__ __launch_bounds__(256) void bn_apply(float* __restrict__ x, int n,
                                                const float* __restrict__ ssum,
                                                const float* __restrict__ ssq,
                                                const float* __restrict__ gamma,
                                                const float* __restrict__ beta)
{
    float inv_n = 1.0f / (float)n;
    size_t total4 = (size_t)n * F / 4;
    for (size_t i = (size_t)blockIdx.x * 256 + threadIdx.x; i < total4;
         i += (size_t)gridDim.x * 256) {
        float4 v = ((const float4*)x)[i];
        int f0 = (int)((i * 4) & (F - 1));
        float in[4] = {v.x, v.y, v.z, v.w};
#pragma unroll
        for (int k = 0; k < 4; ++k) {
            int f = f0 + k;
            float mean = ssum[f] * inv_n;
            float var = ssq[f] * inv_n - mean * mean;
            float sc = rsqrtf(var + BN_EPS) * gamma[f];
            in[k] = (in[k] - mean) * sc + beta[f];
        }
        v.x = in[0]; v.y = in[1]; v.z = in[2]; v.w = in[3];
        ((float4*)x)[i] = v;
    }
}

// ---------------- launch ----------------
extern "C" void kernel_launch(void* const* d_in, const int* in_sizes, int n_in,
                              void* d_out, int out_size, void* d_ws, size_t ws_size,
                              hipStream_t stream) {
    const float* x       = (const float*)d_in[0];
    const int*   adj_row = (const int*)d_in[1];
    const int*   adj_col = (const int*)d_in[2];
    const float* adj_val = (const float*)d_in[3];
    const float* W1      = (const float*)d_in[4];
    const float* b1      = (const float*)d_in[5];
    const float* gamma1  = (const float*)d_in[6];
    const float* beta1   = (const float*)d_in[7];
    const float* Wa1     = (const float*)d_in[8];
    const float* ba1     = (const float*)d_in[9];
    const float* Wa2     = (const float*)d_in[10];
    const float* ba2     = (const float*)d_in[11];
    const float* W2      = (const float*)d_in[12];
    const float* b2      = (const float*)d_in[13];
    const float* gamma2  = (const float*)d_in[14];
    const float* beta2   = (const float*)d_in[15];

    const int N = in_sizes[0] / IN_DIM;   // 100000
    const int E = in_sizes[1];            // 3200000

    char* ws = (char*)d_ws;
    size_t off = 0;
    auto alloc = [&](size_t bytes) -> void* {
        void* p = ws + off;
        off = (off + bytes + 255) & ~(size_t)255;
        return p;
    };
    float* bufA   = (float*)alloc((size_t)N * HID * 4);       // support1 -> support2
    float* bufB   = (float*)alloc((size_t)N * HID * 4);       // x1 (gated in place)
    float* bufH   = (float*)alloc((size_t)N * (HID / 4) * 4); // attn hidden
    int*   scol   = (int*)alloc((size_t)E * 4);
    float* sval   = (float*)alloc((size_t)E * 4);
    int*   counts = (int*)alloc((size_t)N * 4);
    int*   row_st = (int*)alloc((size_t)N * 4);
    int*   cur_of = (int*)alloc((size_t)N * 4);
    int*   bsums  = (int*)alloc(4096);
    float* stats  = (float*)alloc(1536 * 4);
    float* ssum1 = stats, *ssq1 = stats + 512, *ssum2 = stats + 1024, *ssq2 = stats + 1280;

    const int nb_n = (N + 255) / 256;   // 391
    const int nb_e = (E + 255) / 256;

    // CSR build
    zero_kernel<<<nb_n, 256, 0, stream>>>(counts, N);
    zero_kernel<<<6, 256, 0, stream>>>((int*)stats, 1536);
    count_edges<<<nb_e, 256, 0, stream>>>(adj_row, E, counts);
    scan_block<256><<<nb_n, 256, 0, stream>>>(counts, N, row_st, bsums);
    scan_block<512><<<1, 512, 0, stream>>>(bsums, nb_n, bsums, nullptr);
    scan_add<<<nb_n, 256, 0, stream>>>(row_st, cur_of, bsums, N);
    scatter_edges<<<nb_e, 256, 0, stream>>>(adj_row, adj_col, adj_val, E, cur_of, scol, sval);

    // layer 1
    dim3 g1((N + 63) / 64, HID / 64);
    gemm_kernel<0><<<g1, 256, 0, stream>>>(x, W1, bufA, nullptr, nullptr, N, HID, IN_DIM);
    spmm_bias_gelu<HID><<<N, 256, 0, stream>>>(bufA, scol, sval, row_st, counts, b1, bufB, N);
    bn_reduce<HID><<<nb_n, 256, 0, stream>>>(bufB, N, ssum1, ssq1);
    bn_apply<HID><<<2048, 256, 0, stream>>>(bufB, N, ssum1, ssq1, gamma1, beta1);

    // attention gate (in place on bufB)
    dim3 g2((N + 63) / 64, (HID / 4) / 64);
    gemm_kernel<1><<<g2, 256, 0, stream>>>(bufB, Wa1, bufH, ba1, nullptr, N, HID / 4, HID);
    dim3 g3((N + 63) / 64, HID / 64);
    gemm_kernel<2><<<g3, 256, 0, stream>>>(bufH, Wa2, bufB, ba2, bufB, N, HID, HID / 4);

    // layer 2
    dim3 g4((N + 63) / 64, OUT_DIM / 64);
    gemm_kernel<0><<<g4, 256, 0, stream>>>(bufB, W2, bufA, nullptr, nullptr, N, OUT_DIM, HID);
    spmm_bias_gelu<OUT_DIM><<<N, 256, 0, stream>>>(bufA, scol, sval, row_st, counts, b2,
                                                   (float*)d_out, N);
    bn_reduce<OUT_DIM><<<nb_n, 256, 0, stream>>>((float*)d_out, N, ssum2, ssq2);
    bn_apply<OUT_DIM><<<2048, 256, 0, stream>>>((float*)d_out, N, ssum2, ssq2, gamma2, beta2);
}

// Round 2
// 2144.391 us; speedup vs baseline: 1.8033x; 1.8033x over previous
//
#include <hip/hip_runtime.h>
#include <cstdint>
#include <cstddef>

#define IN_DIM 512
#define HID 512
#define OUT_DIM 256
#define BN_EPS 1e-5f

typedef unsigned short u16;
typedef short s16x8 __attribute__((ext_vector_type(8)));
typedef float f32x4 __attribute__((ext_vector_type(4)));

__device__ __forceinline__ float gelu_f(float x) {
    return 0.5f * x * (1.0f + erff(x * 0.70710678118654752f));
}
__device__ __forceinline__ float bflo(uint32_t p) {
    uint32_t t = p << 16; float f; __builtin_memcpy(&f, &t, 4); return f;
}
__device__ __forceinline__ float bfhi(uint32_t p) {
    uint32_t t = p & 0xffff0000u; float f; __builtin_memcpy(&f, &t, 4); return f;
}
__device__ __forceinline__ float bfu(u16 u) {
    uint32_t t = (uint32_t)u << 16; float f; __builtin_memcpy(&f, &t, 4); return f;
}
__device__ __forceinline__ u16 f2bf(float f) {   // round-to-nearest-even
    uint32_t x; __builtin_memcpy(&x, &f, 4);
    uint32_t r = x + 0x7fffu + ((x >> 16) & 1u);
    return (u16)(r >> 16);
}
__device__ __forceinline__ void gld_lds16(void* lds, const void* gp) {
    // gfx950 async global->LDS, 16B per lane; LDS dest = wave-uniform base + lane*16
    __builtin_amdgcn_global_load_lds(
        (const __attribute__((address_space(1))) void*)gp,
        (__attribute__((address_space(3))) void*)lds, 16, 0, 0);
}

// ---------------- utility ----------------
__global__ void zero_kernel(int* __restrict__ p, int n) {
    int i = blockIdx.x * 256 + threadIdx.x;
    if (i < n) p[i] = 0;
}

// ---------------- CSR build ----------------
__global__ void count_edges(const int* __restrict__ row, int ne, int* __restrict__ counts) {
    int e = blockIdx.x * 256 + threadIdx.x;
    if (e < ne) atomicAdd(&counts[row[e]], 1);
}

template<int BS>
__global__ void scan_block(const int* __restrict__ in, int n,
                           int* __restrict__ out, int* __restrict__ bsums) {
    __shared__ int tmp[BS];
    int t = threadIdx.x;
    int gid = blockIdx.x * BS + t;
    int v = (gid < n) ? in[gid] : 0;
    tmp[t] = v;
    __syncthreads();
    for (int off = 1; off < BS; off <<= 1) {
        int add = (t >= off) ? tmp[t - off] : 0;
        __syncthreads();
        tmp[t] += add;
        __syncthreads();
    }
    if (gid < n) out[gid] = tmp[t] - v;   // exclusive
    if (t == BS - 1 && bsums) bsums[blockIdx.x] = tmp[t];
}

__global__ void scan_add(int* __restrict__ row_start, int* __restrict__ cur_off,
                         const int* __restrict__ bsums, int n) {
    int gid = blockIdx.x * 256 + threadIdx.x;
    if (gid < n) {
        int v = row_start[gid] + bsums[blockIdx.x];
        row_start[gid] = v;
        cur_off[gid] = v;
    }
}

__global__ void scatter_edges(const int* __restrict__ row, const int* __restrict__ col,
                              const float* __restrict__ val, int ne,
                              int* __restrict__ cur_off, int2* __restrict__ epk) {
    int e = blockIdx.x * 256 + threadIdx.x;
    if (e < ne) {
        int r = row[e];
        int p = atomicAdd(&cur_off[r], 1);
        epk[p] = make_int2(col[e], __float_as_int(val[e]));
    }
}

// ---------------- casts ----------------
__global__ __launch_bounds__(256) void cast_to_bf16(const float* __restrict__ in,
                                                    u16* __restrict__ out, size_t n) {
    size_t base = ((size_t)blockIdx.x * 256 + threadIdx.x) * 8;
    if (base >= n) return;
    float4 a = *(const float4*)(in + base);
    float4 b = *(const float4*)(in + base + 4);
    u16 o[8] = {f2bf(a.x), f2bf(a.y), f2bf(a.z), f2bf(a.w),
                f2bf(b.x), f2bf(b.y), f2bf(b.z), f2bf(b.w)};
    uint4 pk; __builtin_memcpy(&pk, o, 16);
    *(uint4*)(out + base) = pk;
}

// in[K,N] fp32 -> out[N,K] bf16
__global__ __launch_bounds__(256) void transpose_cast(const float* __restrict__ in,
                                                      u16* __restrict__ out, int K, int N) {
    __shared__ float t[32][33];
    int tx = threadIdx.x & 31, ty = threadIdx.x >> 5;
    int k0 = blockIdx.x * 32, n0 = blockIdx.y * 32;
#pragma unroll
    for (int i = ty; i < 32; i += 8) t[i][tx] = in[(size_t)(k0 + i) * N + n0 + tx];
    __syncthreads();
#pragma unroll
    for (int i = ty; i < 32; i += 8) out[(size_t)(n0 + i) * K + k0 + tx] = f2bf(t[tx][i]);
}

// ---------------- bf16 MFMA GEMM: C[M,N] = A[M,K] @ Bt[N,K]^T ----------------
// EPI: 0 = none, 1 = relu(acc+bias), 2 = extra * sigmoid(acc+bias). C is bf16.
template<int EPI>
__global__ __launch_bounds__(256) void gemm_bt(
    const u16* __restrict__ A, const u16* __restrict__ Bt,
    u16* __restrict__ C, const float* __restrict__ bias,
    const u16* __restrict__ extra, int M, int N, int K)
{
    __shared__ u16 Alds[128 * 32];
    __shared__ u16 Blds[128 * 32];
    const int tid = threadIdx.x;
    const int wid = tid >> 6, lane = tid & 63;
    const int wm = wid >> 1, wn = wid & 1;
    const int row0 = blockIdx.x * 128, col0 = blockIdx.y * 128;
    const int srow = lane >> 2;        // 0..15 (row within 16-row staging chunk)
    const int scol = (lane & 3) * 8;   // element offset within 32-elem K chunk
    const int fr = lane & 15;
    const int fk = (lane >> 4) * 8;

    f32x4 acc[4][4];
#pragma unroll
    for (int i = 0; i < 4; ++i)
#pragma unroll
        for (int j = 0; j < 4; ++j) acc[i][j] = f32x4{0.f, 0.f, 0.f, 0.f};

    for (int k0 = 0; k0 < K; k0 += 32) {
#pragma unroll
        for (int c = 0; c < 2; ++c) {
            int tr = wid * 32 + c * 16 + srow;       // tile row 0..127
            int ar = row0 + tr; if (ar >= M) ar = M - 1;
            gld_lds16(&Alds[(wid * 32 + c * 16) * 32], A + (size_t)ar * K + k0 + scol);
            gld_lds16(&Blds[(wid * 32 + c * 16) * 32], Bt + (size_t)(col0 + tr) * K + k0 + scol);
        }
        __syncthreads();   // compiler drains vmcnt before s_barrier
        s16x8 af[4], bfv[4];
#pragma unroll
        for (int m = 0; m < 4; ++m)
            af[m] = *(const s16x8*)&Alds[(wm * 64 + m * 16 + fr) * 32 + fk];
#pragma unroll
        for (int n = 0; n < 4; ++n)
            bfv[n] = *(const s16x8*)&Blds[(wn * 64 + n * 16 + fr) * 32 + fk];
#pragma unroll
        for (int m = 0; m < 4; ++m)
#pragma unroll
            for (int n = 0; n < 4; ++n)
                acc[m][n] = __builtin_amdgcn_mfma_f32_16x16x32_bf16(af[m], bfv[n], acc[m][n], 0, 0, 0);
        __syncthreads();
    }

#pragma unroll
    for (int n = 0; n < 4; ++n) {
        const int c = col0 + wn * 64 + n * 16 + fr;
        float bv = 0.f;
        if (EPI != 0) bv = bias[c];
#pragma unroll
        for (int m = 0; m < 4; ++m) {
            const int rbase = row0 + wm * 64 + m * 16 + (lane >> 4) * 4;
#pragma unroll
            for (int q = 0; q < 4; ++q) {
                int rr = rbase + q;
                if (rr < M) {
                    float v = acc[m][n][q];
                    if (EPI == 1) v = fmaxf(v + bv, 0.f);
                    else if (EPI == 2) {
                        float ev = bfu(extra[(size_t)rr * N + c]);
                        v = ev / (1.f + expf(-(v + bv)));
                    }
                    C[(size_t)rr * N + c] = f2bf(v);
                }
            }
        }
    }
}

// ---------------- SpMM (CSR gather, bf16 support) + bias + GELU ----------------
template<int F, bool OUTBF>
__global__ __launch_bounds__(F / 2) void spmm_bg(
    const u16* __restrict__ sup, const int2* __restrict__ epk,
    const int* __restrict__ row_start, const int* __restrict__ counts,
    const float* __restrict__ bias, float* __restrict__ outf,
    u16* __restrict__ outb, int n)
{
    const int row = blockIdx.x;
    const int tid = threadIdx.x;
    const int start = row_start[row];
    const int nnz = counts[row];
    const uint32_t* supu = (const uint32_t*)sup;
    float a0 = 0.f, a1 = 0.f;
    int j = 0;
    for (; j + 1 < nnz; j += 2) {
        int2 e0 = epk[start + j], e1 = epk[start + j + 1];
        uint32_t p0 = supu[(size_t)e0.x * (F / 2) + tid];
        uint32_t p1 = supu[(size_t)e1.x * (F / 2) + tid];
        float v0 = __int_as_float(e0.y), v1 = __int_as_float(e1.y);
        a0 = fmaf(v0, bflo(p0), a0); a1 = fmaf(v0, bfhi(p0), a1);
        a0 = fmaf(v1, bflo(p1), a0); a1 = fmaf(v1, bfhi(p1), a1);
    }
    if (j < nnz) {
        int2 e = epk[start + j];
        uint32_t p = supu[(size_t)e.x * (F / 2) + tid];
        float v = __int_as_float(e.y);
        a0 = fmaf(v, bflo(p), a0); a1 = fmaf(v, bfhi(p), a1);
    }
    float o0 = gelu_f(a0 + bias[2 * tid]);
    float o1 = gelu_f(a1 + bias[2 * tid + 1]);
    if (OUTBF) {
        uint32_t pk = (uint32_t)f2bf(o0) | ((uint32_t)f2bf(o1) << 16);
        ((uint32_t*)outb)[(size_t)row * (F / 2) + tid] = pk;
    } else {
        *(float2*)&outf[(size_t)row * F + 2 * tid] = make_float2(o0, o1);
    }
}

// ---------------- BatchNorm (bf16 in-place, F=512 path) ----------------
template<int F>
__global__ __launch_bounds__(256) void bn_reduce_bf16(const u16* __restrict__ x, int n,
                                                      float* __restrict__ ssum,
                                                      float* __restrict__ ssq) {
    const int tid = threadIdx.x;            // feature pair index (F/2 == 256)
    int r0 = blockIdx.x * 256, rend = min(r0 + 256, n);
    const uint32_t* xu = (const uint32_t*)x;
    float s0 = 0, s1 = 0, q0 = 0, q1 = 0;
    for (int r = r0; r < rend; ++r) {
        uint32_t p = xu[(size_t)r * (F / 2) + tid];
        float v0 = bflo(p), v1 = bfhi(p);
        s0 += v0; q0 += v0 * v0;
        s1 += v1; q1 += v1 * v1;
    }
    atomicAdd(&ssum[2 * tid], s0);     atomicAdd(&ssum[2 * tid + 1], s1);
    atomicAdd(&ssq[2 * tid], q0);      atomicAdd(&ssq[2 * tid + 1], q1);
}

template<int F>
__global__ __launch_bounds__(256) void bn_apply_bf16(u16* __restrict__ x, int n,
                                                     const float* __restrict__ ssum,
                                                     const float* __restrict__ ssq,
                                                     const float* __restrict__ gamma,
                                                     const float* __restrict__ beta) {
    float inv_n = 1.0f / (float)n;
    size_t total = (size_t)n * (F / 2);
    uint32_t* xu = (uint32_t*)x;
    for (size_t i = (size_t)blockIdx.x * 256 + threadIdx.x; i < total;
         i += (size_t)gridDim.x * 256) {
        int f0 = (int)((i * 2) & (size_t)(F - 1));
        uint32_t p = xu[i];
        float m0 = ssum[f0] * inv_n, m1 = ssum[f0 + 1] * inv_n;
        float sc0 = rsqrtf(ssq[f0] * inv_n - m0 * m0 + BN_EPS) * gamma[f0];
        float sc1 = rsqrtf(ssq[f0 + 1] * inv_n - m1 * m1 + BN_EPS) * gamma[f0 + 1];
        float v0 = (bflo(p) - m0) * sc0 + beta[f0];
        float v1 = (bfhi(p) - m1) * sc1 + beta[f0 + 1];
        xu[i] = (uint32_t)f2bf(v0) | ((uint32_t)f2bf(v1) << 16);
    }
}

// ---------------- BatchNorm (fp32, final layer) ----------------
template<int F>
__global__ __launch_bounds__(256) void bn_reduce(const float* __restrict__ x, int n,
                                                 float* __restrict__ ssum, float* __restrict__ ssq) {
    constexpr int NV = F / 256;
    int tid = threadIdx.x;
    int r0 = blockIdx.x * 256, rend = min(r0 + 256, n);
    float s[NV] = {}, q[NV] = {};
    for (int r = r0; r < rend; ++r) {
#pragma unroll
        for (int k = 0; k < NV; ++k) {
            float v = x[(size_t)r * F + tid + k * 256];
            s[k] += v; q[k] += v * v;
        }
    }
#pragma unroll
    for (int k = 0; k < NV; ++k) {
        atomicAdd(&ssum[tid + k * 256], s[k]);
        atomicAdd(&ssq[tid + k * 256], q[k]);
    }
}

template<int F>
__global__ __launch_bounds__(256) void bn_apply(float* __restrict__ x, int n,
                                                const float* __restrict__ ssum,
                                                const float* __restrict__ ssq,
                                                const float* __restrict__ gamma,
                                                const float* __restrict__ beta) {
    float inv_n = 1.0f / (float)n;
    size_t total4 = (size_t)n * F / 4;
    for (size_t i = (size_t)blockIdx.x * 256 + threadIdx.x; i < total4;
         i += (size_t)gridDim.x * 256) {
        float4 v = ((const float4*)x)[i];
        int f0 = (int)((i * 4) & (size_t)(F - 1));
        float in[4] = {v.x, v.y, v.z, v.w};
#pragma unroll
        for (int k = 0; k < 4; ++k) {
            int f = f0 + k;
            float mean = ssum[f] * inv_n;
            float var = ssq[f] * inv_n - mean * mean;
            float sc = rsqrtf(var + BN_EPS) * gamma[f];
            in[k] = (in[k] - mean) * sc + beta[f];
        }
        v.x = in[0]; v.y = in[1]; v.z = in[2]; v.w = in[3];
        ((float4*)x)[i] = v;
    }
}

// ---------------- launch ----------------
extern "C" void kernel_launch(void* const* d_in, const int* in_sizes, int n_in,
                              void* d_out, int out_size, void* d_ws, size_t ws_size,
                              hipStream_t stream) {
    const float* x       = (const float*)d_in[0];
    const int*   adj_row = (const int*)d_in[1];
    const int*   adj_col = (const int*)d_in[2];
    const float* adj_val = (const float*)d_in[3];
    const float* W1      = (const float*)d_in[4];
    const float* b1      = (const float*)d_in[5];
    const float* gamma1  = (const float*)d_in[6];
    const float* beta1   = (const float*)d_in[7];
    const float* Wa1     = (const float*)d_in[8];
    const float* ba1     = (const float*)d_in[9];
    const float* Wa2     = (const float*)d_in[10];
    const float* ba2     = (const float*)d_in[11];
    const float* W2      = (const float*)d_in[12];
    const float* b2      = (const float*)d_in[13];
    const float* gamma2  = (const float*)d_in[14];
    const float* beta2   = (const float*)d_in[15];

    const int N = in_sizes[0] / IN_DIM;   // 100000
    const int E = in_sizes[1];            // 3200000

    char* ws = (char*)d_ws;
    size_t off = 0;
    auto alloc = [&](size_t bytes) -> void* {
        void* p = ws + off;
        off = (off + bytes + 255) & ~(size_t)255;
        return p;
    };
    u16*  x16    = (u16*)alloc((size_t)N * IN_DIM * 2);   // x bf16; reused as gated16
    u16*  sup16  = (u16*)alloc((size_t)N * HID * 2);      // support1, then support2
    u16*  x1_16  = (u16*)alloc((size_t)N * HID * 2);      // x1 bf16 (in-place BN1)
    u16*  h16    = (u16*)alloc((size_t)N * (HID / 4) * 2);
    int2* epk    = (int2*)alloc((size_t)E * 8);
    int*  counts = (int*)alloc((size_t)N * 4);
    int*  row_st = (int*)alloc((size_t)N * 4);
    int*  cur_of = (int*)alloc((size_t)N * 4);
    int*  bsums  = (int*)alloc(4096);
    float* stats = (float*)alloc(1536 * 4);
    u16*  W1t    = (u16*)alloc(512 * 512 * 2);
    u16*  Wa1t   = (u16*)alloc(128 * 512 * 2);
    u16*  Wa2t   = (u16*)alloc(512 * 128 * 2);
    u16*  W2t    = (u16*)alloc(256 * 512 * 2);
    float* ssum1 = stats, *ssq1 = stats + 512, *ssum2 = stats + 1024, *ssq2 = stats + 1280;
    u16*  gated16 = x16;   // reuse after gemm1 consumed x16

    const int nb_n = (N + 255) / 256;   // 391
    const int nb_e = (E + 255) / 256;
    const int gm = (N + 127) / 128;     // 782

    // CSR build + stat zero
    zero_kernel<<<nb_n, 256, 0, stream>>>(counts, N);
    zero_kernel<<<6, 256, 0, stream>>>((int*)stats, 1536);
    count_edges<<<nb_e, 256, 0, stream>>>(adj_row, E, counts);
    scan_block<256><<<nb_n, 256, 0, stream>>>(counts, N, row_st, bsums);
    scan_block<512><<<1, 512, 0, stream>>>(bsums, nb_n, bsums, nullptr);
    scan_add<<<nb_n, 256, 0, stream>>>(row_st, cur_of, bsums, N);
    scatter_edges<<<nb_e, 256, 0, stream>>>(adj_row, adj_col, adj_val, E, cur_of, epk);

    // casts
    cast_to_bf16<<<(int)(((size_t)N * IN_DIM + 2047) / 2048), 256, 0, stream>>>(x, x16, (size_t)N * IN_DIM);
    transpose_cast<<<dim3(16, 16), 256, 0, stream>>>(W1, W1t, IN_DIM, HID);
    transpose_cast<<<dim3(16, 4), 256, 0, stream>>>(Wa1, Wa1t, HID, HID / 4);
    transpose_cast<<<dim3(4, 16), 256, 0, stream>>>(Wa2, Wa2t, HID / 4, HID);
    transpose_cast<<<dim3(16, 8), 256, 0, stream>>>(W2, W2t, HID, OUT_DIM);

    // layer 1
    gemm_bt<0><<<dim3(gm, HID / 128), 256, 0, stream>>>(x16, W1t, sup16, nullptr, nullptr, N, HID, IN_DIM);
    spmm_bg<HID, true><<<N, HID / 2, 0, stream>>>(sup16, epk, row_st, counts, b1, nullptr, x1_16, N);
    bn_reduce_bf16<HID><<<nb_n, 256, 0, stream>>>(x1_16, N, ssum1, ssq1);
    bn_apply_bf16<HID><<<2048, 256, 0, stream>>>(x1_16, N, ssum1, ssq1, gamma1, beta1);

    // attention gate
    gemm_bt<1><<<dim3(gm, 1), 256, 0, stream>>>(x1_16, Wa1t, h16, ba1, nullptr, N, HID / 4, HID);
    gemm_bt<2><<<dim3(gm, HID / 128), 256, 0, stream>>>(h16, Wa2t, gated16, ba2, x1_16, N, HID, HID / 4);

    // layer 2
    gemm_bt<0><<<dim3(gm, OUT_DIM / 128), 256, 0, stream>>>(gated16, W2t, sup16, nullptr, nullptr, N, OUT_DIM, HID);
    spmm_bg<OUT_DIM, false><<<N, OUT_DIM / 2, 0, stream>>>(sup16, epk, row_st, counts, b2, (float*)d_out, nullptr, N);
    bn_reduce<OUT_DIM><<<nb_n, 256, 0, stream>>>((float*)d_out, N, ssum2, ssq2);
    bn_apply<OUT_DIM><<<2048, 256, 0, stream>>>((float*)d_out, N, ssum2, ssq2, gamma2, beta2);
}